// Round 3
// baseline (500.100 us; speedup 1.0000x reference)
//
#include <hip/hip_runtime.h>
#include <hip/hip_bf16.h>

// GraphSAGE 2-layer encoder, MI355X. Round 3.
// - GEMMs: 64-row x full-256-col blocks; whole K staged once into 32KB LDS via
//   global_load_lds(16B), XOR-swizzled vs 512B row stride; weights bf16-packed,
//   streamed from L2. One barrier per block.
// - Aggregation: feature dim chunked into 4 x 64B passes (gridDim.y) so the
//   gather working set (3.2 MB) is L2-resident; wave = 4 edges x 16 lanes,
//   shfl_xor reduction.
// - Layer 2 reassociated: z = h@W2l^T first, gather 128-wide z rows.

typedef short short8 __attribute__((ext_vector_type(8)));
typedef float floatx4 __attribute__((ext_vector_type(4)));

#define IN_C  128
#define HID_C 256
#define OUT_C 128

static __device__ __forceinline__ unsigned short f2b(float f) {
  union { float f; unsigned u; } v; v.f = f;
  unsigned r = v.u + 0x7fffu + ((v.u >> 16) & 1u);   // RNE
  return (unsigned short)(r >> 16);
}
static __device__ __forceinline__ unsigned pack2(float a, float b) {
  return (unsigned)f2b(a) | ((unsigned)f2b(b) << 16);
}
static __device__ __forceinline__ float lo2f(unsigned u) {
  union { unsigned u; float f; } v; v.u = u << 16; return v.f;
}
static __device__ __forceinline__ float hi2f(unsigned u) {
  union { unsigned u; float f; } v; v.u = u & 0xffff0000u; return v.f;
}

// ---------------- CSR build ----------------

__global__ void k_hist(const int* __restrict__ ei, int E, int* __restrict__ deg) {
  int e = blockIdx.x * blockDim.x + threadIdx.x;
  if (e < E) atomicAdd(&deg[ei[E + e]], 1);
}

__global__ void k_scan(const int* __restrict__ deg, int* __restrict__ offs,
                       int* __restrict__ cursor, int n) {
  __shared__ int wsum[16];
  __shared__ int carry_s;
  int tid = threadIdx.x, lane = tid & 63, wv = tid >> 6;
  if (tid == 0) carry_s = 0;
  __syncthreads();
  for (int base = 0; base < n; base += 1024) {
    int idx = base + tid;
    int v = (idx < n) ? deg[idx] : 0;
    int s = v;
#pragma unroll
    for (int off = 1; off < 64; off <<= 1) {
      int t = __shfl_up(s, off, 64);
      if (lane >= off) s += t;
    }
    if (lane == 63) wsum[wv] = s;
    __syncthreads();
    if (wv == 0 && lane < 16) {
      int t = wsum[lane];
#pragma unroll
      for (int off = 1; off < 16; off <<= 1) {
        int u = __shfl_up(t, off, 64);
        if (lane >= off) t += u;
      }
      wsum[lane] = t;
    }
    __syncthreads();
    int woff = (wv == 0) ? 0 : wsum[wv - 1];
    int carry = carry_s;
    int excl = carry + woff + s - v;
    if (idx < n) { offs[idx] = excl; cursor[idx] = excl; }
    __syncthreads();
    if (tid == 0) carry_s = carry + wsum[15];
    __syncthreads();
  }
  if (tid == 0) offs[n] = carry_s;
}

__global__ void k_scatter(const int* __restrict__ ei, int E,
                          int* __restrict__ cursor, int* __restrict__ srcs) {
  int e = blockIdx.x * blockDim.x + threadIdx.x;
  if (e < E) {
    int d = ei[E + e];
    int pos = atomicAdd(&cursor[d], 1);
    srcs[pos] = ei[e];
  }
}

// ---------------- casts / packing ----------------

__global__ void k_cast(const float* __restrict__ in, unsigned* __restrict__ out, int nPairs) {
  int i = blockIdx.x * blockDim.x + threadIdx.x;
  int stride = gridDim.x * blockDim.x;
  for (; i < nPairs; i += stride) {
    float2 v = reinterpret_cast<const float2*>(in)[i];
    out[i] = pack2(v.x, v.y);
  }
}

// Wpk1 row n (128 uints) = [W1l row n (64 pairs) | W1r row n (64 pairs)]
__global__ void k_pack1(const float* __restrict__ Wl, const float* __restrict__ Wr,
                        unsigned* __restrict__ out) {
  int i = blockIdx.x * blockDim.x + threadIdx.x;    // 256*128 pairs
  if (i >= 256 * 128) return;
  int r = i >> 7, c = i & 127;
  const float* src = (c < 64) ? (Wl + (size_t)r * 128 + c * 2)
                              : (Wr + (size_t)r * 128 + (c - 64) * 2);
  float2 v = *reinterpret_cast<const float2*>(src);
  out[i] = pack2(v.x, v.y);
}

// ---------------- chunked mean aggregation ----------------
// Z: N x 64 uints (128 bf16). blockIdx.y = chunk (16 uints = 64B of the row).
// Wave per node: lane = g*16 + c; group g walks edges beg+g, beg+g+4, ...

__global__ void k_agg_store(const unsigned* __restrict__ Z,
                            const int* __restrict__ offs, const int* __restrict__ srcs,
                            unsigned* __restrict__ out, int N) {
  int node = blockIdx.x * 4 + (threadIdx.x >> 6);
  if (node >= N) return;
  int lane = threadIdx.x & 63;
  int g = lane >> 4, c = lane & 15;
  int col = blockIdx.y * 16 + c;
  int beg = offs[node], end = offs[node + 1];
  float s0 = 0.f, s1 = 0.f;
  for (int j = beg + g; j < end; j += 4) {
    unsigned p = Z[(size_t)srcs[j] * 64 + col];
    s0 += lo2f(p); s1 += hi2f(p);
  }
  s0 += __shfl_xor(s0, 16); s1 += __shfl_xor(s1, 16);
  s0 += __shfl_xor(s0, 32); s1 += __shfl_xor(s1, 32);
  if (g == 0) {
    int d = end - beg;
    float inv = 1.0f / (float)(d > 0 ? d : 1);
    out[(size_t)node * 64 + col] = pack2(s0 * inv, s1 * inv);
  }
}

__global__ void k_agg_addout(const unsigned* __restrict__ Z,
                             const int* __restrict__ offs, const int* __restrict__ srcs,
                             float* __restrict__ Out, int N) {
  int node = blockIdx.x * 4 + (threadIdx.x >> 6);
  if (node >= N) return;
  int lane = threadIdx.x & 63;
  int g = lane >> 4, c = lane & 15;
  int col = blockIdx.y * 16 + c;
  int beg = offs[node], end = offs[node + 1];
  float s0 = 0.f, s1 = 0.f;
  for (int j = beg + g; j < end; j += 4) {
    unsigned p = Z[(size_t)srcs[j] * 64 + col];
    s0 += lo2f(p); s1 += hi2f(p);
  }
  s0 += __shfl_xor(s0, 16); s1 += __shfl_xor(s1, 16);
  s0 += __shfl_xor(s0, 32); s1 += __shfl_xor(s1, 32);
  if (g == 0) {
    int d = end - beg;
    float inv = 1.0f / (float)(d > 0 ? d : 1);
    float2* op = reinterpret_cast<float2*>(Out + (size_t)node * 128 + col * 2);
    float2 v = *op;
    v.x += s0 * inv; v.y += s1 * inv;
    *op = v;
  }
}

// ---------------- GEMMs ----------------
// Tile: 64 rows x 256 cols, K=256 staged once in LDS (32KB, XOR-swizzled).
// LDS chunk (16B) at row r, position p holds data chunk d = (p&16)|((p^r)&15).
// Wave w -> cols w*64 + t*16 + l15, t=0..3. MFMA 16x16x32 bf16.
// Frag layouts (m89-verified): A[m=l15][k=quad*8+j]; B=W-row frag; D[row=quad*4+r][col=l15].

static __device__ __forceinline__ void stage_dual(
    const unsigned short* A1, const unsigned short* A2, int mBase,
    unsigned short* At /* LDS 64x256 */) {
  int t = threadIdx.x;
#pragma unroll
  for (int it = 0; it < 8; ++it) {
    int q = it * 256 + t;
    int r = q >> 5;
    int p = q & 31;
    int d = (p & 16) | ((p ^ r) & 15);
    const unsigned short* g = (d < 16)
        ? (A1 + (size_t)(mBase + r) * 128 + d * 8)
        : (A2 + (size_t)(mBase + r) * 128 + (d - 16) * 8);
    __builtin_amdgcn_global_load_lds(
        (const __attribute__((address_space(1))) unsigned*)g,
        (__attribute__((address_space(3))) unsigned*)&At[q * 8], 16, 0, 0);
  }
}

static __device__ __forceinline__ void stage_single(
    const unsigned short* A, int mBase, unsigned short* At) {
  int t = threadIdx.x;
#pragma unroll
  for (int it = 0; it < 8; ++it) {
    int q = it * 256 + t;
    int r = q >> 5;
    int p = q & 31;
    int d = (p & 16) | ((p ^ r) & 15);
    const unsigned short* g = A + (size_t)(mBase + r) * 256 + d * 8;
    __builtin_amdgcn_global_load_lds(
        (const __attribute__((address_space(1))) unsigned*)g,
        (__attribute__((address_space(3))) unsigned*)&At[q * 8], 16, 0, 0);
  }
}

// layer 1: H = relu([agg1|xb] @ Wpk1^T + b1), H bf16 N x 256
__global__ void __launch_bounds__(256, 2)
k_gemm1(const unsigned short* __restrict__ A1, const unsigned short* __restrict__ A2,
        const unsigned short* __restrict__ Wpk, const float* __restrict__ bias,
        unsigned short* __restrict__ H, int M) {
  __shared__ unsigned short At[64 * 256];
  int mBase = blockIdx.x * 64;
  stage_dual(A1, A2, mBase, At);
  int lane = threadIdx.x & 63, wave = threadIdx.x >> 6;
  int l15 = lane & 15, quad = lane >> 4;
  floatx4 acc[4][4] = {};
  __syncthreads();
#pragma unroll 2
  for (int kk = 0; kk < 8; ++kk) {
    int kc = kk * 4 + quad;
    short8 b[4];
#pragma unroll
    for (int t = 0; t < 4; ++t) {
      int n = wave * 64 + t * 16 + l15;
      b[t] = *reinterpret_cast<const short8*>(Wpk + (size_t)n * 256 + kc * 8);
    }
#pragma unroll
    for (int s = 0; s < 4; ++s) {
      int row = s * 16 + l15;
      int pos = (kc & 16) | ((kc ^ row) & 15);
      short8 a = *reinterpret_cast<const short8*>(&At[row * 256 + pos * 8]);
#pragma unroll
      for (int t = 0; t < 4; ++t)
        acc[s][t] = __builtin_amdgcn_mfma_f32_16x16x32_bf16(a, b[t], acc[s][t], 0, 0, 0);
    }
  }
#pragma unroll
  for (int t = 0; t < 4; ++t) {
    int n = wave * 64 + t * 16 + l15;
    float bv = bias[n];
#pragma unroll
    for (int s = 0; s < 4; ++s)
#pragma unroll
      for (int r = 0; r < 4; ++r) {
        int m = mBase + s * 16 + quad * 4 + r;
        if (m < M) H[(size_t)m * 256 + n] = f2b(fmaxf(acc[s][t][r] + bv, 0.f));
      }
  }
}

// layer 2: waves 0,1 -> z = H@W2l^T (bf16); waves 2,3 -> out = H@W2r^T + b2 (f32)
__global__ void __launch_bounds__(256, 2)
k_gemm2(const unsigned short* __restrict__ H, const unsigned short* __restrict__ Wpk,
        const float* __restrict__ bias, unsigned short* __restrict__ Zb,
        float* __restrict__ Out, int M) {
  __shared__ unsigned short At[64 * 256];
  int mBase = blockIdx.x * 64;
  stage_single(H, mBase, At);
  int lane = threadIdx.x & 63, wave = threadIdx.x >> 6;
  int l15 = lane & 15, quad = lane >> 4;
  floatx4 acc[4][4] = {};
  __syncthreads();
#pragma unroll 2
  for (int kk = 0; kk < 8; ++kk) {
    int kc = kk * 4 + quad;
    short8 b[4];
#pragma unroll
    for (int t = 0; t < 4; ++t) {
      int n = wave * 64 + t * 16 + l15;    // 0..255 combined
      b[t] = *reinterpret_cast<const short8*>(Wpk + (size_t)n * 256 + kc * 8);
    }
#pragma unroll
    for (int s = 0; s < 4; ++s) {
      int row = s * 16 + l15;
      int pos = (kc & 16) | ((kc ^ row) & 15);
      short8 a = *reinterpret_cast<const short8*>(&At[row * 256 + pos * 8]);
#pragma unroll
      for (int t = 0; t < 4; ++t)
        acc[s][t] = __builtin_amdgcn_mfma_f32_16x16x32_bf16(a, b[t], acc[s][t], 0, 0, 0);
    }
  }
  if (wave < 2) {        // z path, cols 0..127, bf16, no bias
#pragma unroll
    for (int t = 0; t < 4; ++t) {
      int n = wave * 64 + t * 16 + l15;
#pragma unroll
      for (int s = 0; s < 4; ++s)
#pragma unroll
        for (int r = 0; r < 4; ++r) {
          int m = mBase + s * 16 + quad * 4 + r;
          if (m < M) Zb[(size_t)m * 128 + n] = f2b(acc[s][t][r]);
        }
    }
  } else {               // out path, cols 0..127 of Out, f32 + bias
#pragma unroll
    for (int t = 0; t < 4; ++t) {
      int n = (wave - 2) * 64 + t * 16 + l15;
      float bv = bias[n];
#pragma unroll
      for (int s = 0; s < 4; ++s)
#pragma unroll
        for (int r = 0; r < 4; ++r) {
          int m = mBase + s * 16 + quad * 4 + r;
          if (m < M) Out[(size_t)m * 128 + n] = acc[s][t][r] + bv;
        }
    }
  }
}

// ---------------- launch ----------------

extern "C" void kernel_launch(void* const* d_in, const int* in_sizes, int n_in,
                              void* d_out, int out_size, void* d_ws, size_t ws_size,
                              hipStream_t stream) {
  const float* x   = (const float*)d_in[0];
  const int*   ei  = (const int*)d_in[1];
  const float* W1l = (const float*)d_in[2];
  const float* b1  = (const float*)d_in[3];
  const float* W1r = (const float*)d_in[4];
  const float* W2l = (const float*)d_in[5];
  const float* b2  = (const float*)d_in[6];
  const float* W2r = (const float*)d_in[7];
  float* out = (float*)d_out;

  int N = in_sizes[0] / IN_C;   // 50000
  int E = in_sizes[1] / 2;      // 800000

  char* p = (char*)d_ws;
  auto alloc = [&](size_t bytes) -> void* {
    void* r = (void*)p;
    p += (bytes + 255) & ~(size_t)255;
    return r;
  };
  int* deg    = (int*)alloc((size_t)N * 4);
  int* offs   = (int*)alloc(((size_t)N + 1) * 4);
  int* cursor = (int*)alloc((size_t)N * 4);
  int* srcs   = (int*)alloc((size_t)E * 4);
  unsigned* xb   = (unsigned*)alloc((size_t)N * IN_C * 2);   // N x 64 uints
  unsigned* agg1 = (unsigned*)alloc((size_t)N * IN_C * 2);
  unsigned short* hb = (unsigned short*)alloc((size_t)N * HID_C * 2);
  unsigned short* zb = (unsigned short*)alloc((size_t)N * OUT_C * 2);
  unsigned* wpk1 = (unsigned*)alloc((size_t)HID_C * 256 * 2);  // 256 x 128 uints
  unsigned* wpk2 = (unsigned*)alloc((size_t)256 * HID_C * 2);  // 256 x 128 uints
  // tail pad so last-block over-reads stay in ws
  (void)alloc(64 * 512);

  // CSR build
  hipMemsetAsync(deg, 0, (size_t)N * 4, stream);
  k_hist<<<(E + 255) / 256, 256, 0, stream>>>(ei, E, deg);
  k_scan<<<1, 1024, 0, stream>>>(deg, offs, cursor, N);
  k_scatter<<<(E + 255) / 256, 256, 0, stream>>>(ei, E, cursor, srcs);

  // casts + weight packing
  k_cast<<<768, 256, 0, stream>>>(x, xb, N * IN_C / 2);
  k_pack1<<<128, 256, 0, stream>>>(W1l, W1r, wpk1);
  k_cast<<<32, 256, 0, stream>>>(W2l, wpk2, OUT_C * HID_C / 2);
  k_cast<<<32, 256, 0, stream>>>(W2r, wpk2 + (size_t)OUT_C * HID_C / 2, OUT_C * HID_C / 2);

  int aggX = (N + 3) / 4;
  int mBlocks = (N + 63) / 64;

  // layer 1
  k_agg_store<<<dim3(aggX, 4), 256, 0, stream>>>(xb, offs, srcs, agg1, N);
  k_gemm1<<<mBlocks, 256, 0, stream>>>(
      (const unsigned short*)agg1, (const unsigned short*)xb,
      (const unsigned short*)wpk1, b1, hb, N);

  // layer 2 (reassociated)
  k_gemm2<<<mBlocks, 256, 0, stream>>>(
      hb, (const unsigned short*)wpk2, b2, zb, out, N);
  k_agg_addout<<<dim3(aggX, 4), 256, 0, stream>>>((const unsigned*)zb, offs, srcs, out, N);
}

// Round 4
// 364.375 us; speedup vs baseline: 1.3725x; 1.3725x over previous
//
#include <hip/hip_runtime.h>
#include <hip/hip_bf16.h>

// GraphSAGE 2-layer encoder, MI355X. Round 4.
// - Aggregation: wave-per-node FULL-ROW gather (256 B/edge, full line use),
//   8-deep edge unroll for MLP (2 KB in flight per wave). No feature chunking
//   (round-3 chunking halved line utilization and MLP -> regressed).
// - GEMMs: round-3 structure kept (64x256 tile, K staged once into 32KB LDS
//   via global_load_lds(16B), XOR swizzle, weights from L2).
// - Layer 2 reassociated: z = h@W2l^T first, gather 128-wide z rows.

typedef short short8 __attribute__((ext_vector_type(8)));
typedef float floatx4 __attribute__((ext_vector_type(4)));

#define IN_C  128
#define HID_C 256
#define OUT_C 128

static __device__ __forceinline__ unsigned short f2b(float f) {
  union { float f; unsigned u; } v; v.f = f;
  unsigned r = v.u + 0x7fffu + ((v.u >> 16) & 1u);   // RNE
  return (unsigned short)(r >> 16);
}
static __device__ __forceinline__ unsigned pack2(float a, float b) {
  return (unsigned)f2b(a) | ((unsigned)f2b(b) << 16);
}
static __device__ __forceinline__ float lo2f(unsigned u) {
  union { unsigned u; float f; } v; v.u = u << 16; return v.f;
}
static __device__ __forceinline__ float hi2f(unsigned u) {
  union { unsigned u; float f; } v; v.u = u & 0xffff0000u; return v.f;
}

// ---------------- CSR build ----------------

__global__ void k_hist(const int* __restrict__ ei, int E, int* __restrict__ deg) {
  int e = blockIdx.x * blockDim.x + threadIdx.x;
  if (e < E) atomicAdd(&deg[ei[E + e]], 1);
}

__global__ void k_scan(const int* __restrict__ deg, int* __restrict__ offs,
                       int* __restrict__ cursor, int n) {
  __shared__ int wsum[16];
  __shared__ int carry_s;
  int tid = threadIdx.x, lane = tid & 63, wv = tid >> 6;
  if (tid == 0) carry_s = 0;
  __syncthreads();
  for (int base = 0; base < n; base += 1024) {
    int idx = base + tid;
    int v = (idx < n) ? deg[idx] : 0;
    int s = v;
#pragma unroll
    for (int off = 1; off < 64; off <<= 1) {
      int t = __shfl_up(s, off, 64);
      if (lane >= off) s += t;
    }
    if (lane == 63) wsum[wv] = s;
    __syncthreads();
    if (wv == 0 && lane < 16) {
      int t = wsum[lane];
#pragma unroll
      for (int off = 1; off < 16; off <<= 1) {
        int u = __shfl_up(t, off, 64);
        if (lane >= off) t += u;
      }
      wsum[lane] = t;
    }
    __syncthreads();
    int woff = (wv == 0) ? 0 : wsum[wv - 1];
    int carry = carry_s;
    int excl = carry + woff + s - v;
    if (idx < n) { offs[idx] = excl; cursor[idx] = excl; }
    __syncthreads();
    if (tid == 0) carry_s = carry + wsum[15];
    __syncthreads();
  }
  if (tid == 0) offs[n] = carry_s;
}

__global__ void k_scatter(const int* __restrict__ ei, int E,
                          int* __restrict__ cursor, int* __restrict__ srcs) {
  int e = blockIdx.x * blockDim.x + threadIdx.x;
  if (e < E) {
    int d = ei[E + e];
    int pos = atomicAdd(&cursor[d], 1);
    srcs[pos] = ei[e];
  }
}

// ---------------- casts / packing ----------------

__global__ void k_cast(const float* __restrict__ in, unsigned* __restrict__ out, int nPairs) {
  int i = blockIdx.x * blockDim.x + threadIdx.x;
  int stride = gridDim.x * blockDim.x;
  for (; i < nPairs; i += stride) {
    float2 v = reinterpret_cast<const float2*>(in)[i];
    out[i] = pack2(v.x, v.y);
  }
}

// Wpk1 row n (128 uints) = [W1l row n (64 pairs) | W1r row n (64 pairs)]
__global__ void k_pack1(const float* __restrict__ Wl, const float* __restrict__ Wr,
                        unsigned* __restrict__ out) {
  int i = blockIdx.x * blockDim.x + threadIdx.x;    // 256*128 pairs
  if (i >= 256 * 128) return;
  int r = i >> 7, c = i & 127;
  const float* src = (c < 64) ? (Wl + (size_t)r * 128 + c * 2)
                              : (Wr + (size_t)r * 128 + (c - 64) * 2);
  float2 v = *reinterpret_cast<const float2*>(src);
  out[i] = pack2(v.x, v.y);
}

// ---------------- mean aggregation: wave per node, full 256 B row ----------------
// Z: N x 64 uints (128 bf16). lane covers cols {2*lane, 2*lane+1}.
// 8-deep edge unroll -> 8 outstanding 256 B wave-loads.

__global__ void k_agg_store(const unsigned* __restrict__ Z,
                            const int* __restrict__ offs, const int* __restrict__ srcs,
                            unsigned* __restrict__ out, int N) {
  int node = blockIdx.x * 4 + (threadIdx.x >> 6);
  if (node >= N) return;
  int lane = threadIdx.x & 63;
  int beg = offs[node], end = offs[node + 1];
  float s0 = 0.f, s1 = 0.f;
  int j = beg;
  for (; j + 8 <= end; j += 8) {
    unsigned p0 = Z[(size_t)srcs[j + 0] * 64 + lane];
    unsigned p1 = Z[(size_t)srcs[j + 1] * 64 + lane];
    unsigned p2 = Z[(size_t)srcs[j + 2] * 64 + lane];
    unsigned p3 = Z[(size_t)srcs[j + 3] * 64 + lane];
    unsigned p4 = Z[(size_t)srcs[j + 4] * 64 + lane];
    unsigned p5 = Z[(size_t)srcs[j + 5] * 64 + lane];
    unsigned p6 = Z[(size_t)srcs[j + 6] * 64 + lane];
    unsigned p7 = Z[(size_t)srcs[j + 7] * 64 + lane];
    s0 += lo2f(p0) + lo2f(p1) + lo2f(p2) + lo2f(p3)
        + lo2f(p4) + lo2f(p5) + lo2f(p6) + lo2f(p7);
    s1 += hi2f(p0) + hi2f(p1) + hi2f(p2) + hi2f(p3)
        + hi2f(p4) + hi2f(p5) + hi2f(p6) + hi2f(p7);
  }
  for (; j < end; ++j) {
    unsigned p = Z[(size_t)srcs[j] * 64 + lane];
    s0 += lo2f(p); s1 += hi2f(p);
  }
  int d = end - beg;
  float inv = 1.0f / (float)(d > 0 ? d : 1);
  out[(size_t)node * 64 + lane] = pack2(s0 * inv, s1 * inv);
}

__global__ void k_agg_addout(const unsigned* __restrict__ Z,
                             const int* __restrict__ offs, const int* __restrict__ srcs,
                             float* __restrict__ Out, int N) {
  int node = blockIdx.x * 4 + (threadIdx.x >> 6);
  if (node >= N) return;
  int lane = threadIdx.x & 63;
  int beg = offs[node], end = offs[node + 1];
  float s0 = 0.f, s1 = 0.f;
  int j = beg;
  for (; j + 8 <= end; j += 8) {
    unsigned p0 = Z[(size_t)srcs[j + 0] * 64 + lane];
    unsigned p1 = Z[(size_t)srcs[j + 1] * 64 + lane];
    unsigned p2 = Z[(size_t)srcs[j + 2] * 64 + lane];
    unsigned p3 = Z[(size_t)srcs[j + 3] * 64 + lane];
    unsigned p4 = Z[(size_t)srcs[j + 4] * 64 + lane];
    unsigned p5 = Z[(size_t)srcs[j + 5] * 64 + lane];
    unsigned p6 = Z[(size_t)srcs[j + 6] * 64 + lane];
    unsigned p7 = Z[(size_t)srcs[j + 7] * 64 + lane];
    s0 += lo2f(p0) + lo2f(p1) + lo2f(p2) + lo2f(p3)
        + lo2f(p4) + lo2f(p5) + lo2f(p6) + lo2f(p7);
    s1 += hi2f(p0) + hi2f(p1) + hi2f(p2) + hi2f(p3)
        + hi2f(p4) + hi2f(p5) + hi2f(p6) + hi2f(p7);
  }
  for (; j < end; ++j) {
    unsigned p = Z[(size_t)srcs[j] * 64 + lane];
    s0 += lo2f(p); s1 += hi2f(p);
  }
  int d = end - beg;
  float inv = 1.0f / (float)(d > 0 ? d : 1);
  float2* op = reinterpret_cast<float2*>(Out + (size_t)node * 128 + lane * 2);
  float2 v = *op;
  v.x += s0 * inv; v.y += s1 * inv;
  *op = v;
}

// ---------------- GEMMs ----------------
// Tile: 64 rows x 256 cols, K=256 staged once in LDS (32KB, XOR-swizzled).
// LDS chunk (16B) at row r, position p holds data chunk d = (p&16)|((p^r)&15).
// Wave w -> cols w*64 + t*16 + l15, t=0..3. MFMA 16x16x32 bf16.

static __device__ __forceinline__ void stage_dual(
    const unsigned short* A1, const unsigned short* A2, int mBase,
    unsigned short* At /* LDS 64x256 */) {
  int t = threadIdx.x;
#pragma unroll
  for (int it = 0; it < 8; ++it) {
    int q = it * 256 + t;
    int r = q >> 5;
    int p = q & 31;
    int d = (p & 16) | ((p ^ r) & 15);
    const unsigned short* g = (d < 16)
        ? (A1 + (size_t)(mBase + r) * 128 + d * 8)
        : (A2 + (size_t)(mBase + r) * 128 + (d - 16) * 8);
    __builtin_amdgcn_global_load_lds(
        (const __attribute__((address_space(1))) unsigned*)g,
        (__attribute__((address_space(3))) unsigned*)&At[q * 8], 16, 0, 0);
  }
}

static __device__ __forceinline__ void stage_single(
    const unsigned short* A, int mBase, unsigned short* At) {
  int t = threadIdx.x;
#pragma unroll
  for (int it = 0; it < 8; ++it) {
    int q = it * 256 + t;
    int r = q >> 5;
    int p = q & 31;
    int d = (p & 16) | ((p ^ r) & 15);
    const unsigned short* g = A + (size_t)(mBase + r) * 256 + d * 8;
    __builtin_amdgcn_global_load_lds(
        (const __attribute__((address_space(1))) unsigned*)g,
        (__attribute__((address_space(3))) unsigned*)&At[q * 8], 16, 0, 0);
  }
}

// layer 1: H = relu([agg1|xb] @ Wpk1^T + b1), H bf16 N x 256
__global__ void __launch_bounds__(256, 2)
k_gemm1(const unsigned short* __restrict__ A1, const unsigned short* __restrict__ A2,
        const unsigned short* __restrict__ Wpk, const float* __restrict__ bias,
        unsigned short* __restrict__ H, int M) {
  __shared__ unsigned short At[64 * 256];
  int mBase = blockIdx.x * 64;
  stage_dual(A1, A2, mBase, At);
  int lane = threadIdx.x & 63, wave = threadIdx.x >> 6;
  int l15 = lane & 15, quad = lane >> 4;
  floatx4 acc[4][4] = {};
  __syncthreads();
#pragma unroll 2
  for (int kk = 0; kk < 8; ++kk) {
    int kc = kk * 4 + quad;
    short8 b[4];
#pragma unroll
    for (int t = 0; t < 4; ++t) {
      int n = wave * 64 + t * 16 + l15;
      b[t] = *reinterpret_cast<const short8*>(Wpk + (size_t)n * 256 + kc * 8);
    }
#pragma unroll
    for (int s = 0; s < 4; ++s) {
      int row = s * 16 + l15;
      int pos = (kc & 16) | ((kc ^ row) & 15);
      short8 a = *reinterpret_cast<const short8*>(&At[row * 256 + pos * 8]);
#pragma unroll
      for (int t = 0; t < 4; ++t)
        acc[s][t] = __builtin_amdgcn_mfma_f32_16x16x32_bf16(a, b[t], acc[s][t], 0, 0, 0);
    }
  }
#pragma unroll
  for (int t = 0; t < 4; ++t) {
    int n = wave * 64 + t * 16 + l15;
    float bv = bias[n];
#pragma unroll
    for (int s = 0; s < 4; ++s)
#pragma unroll
      for (int r = 0; r < 4; ++r) {
        int m = mBase + s * 16 + quad * 4 + r;
        if (m < M) H[(size_t)m * 256 + n] = f2b(fmaxf(acc[s][t][r] + bv, 0.f));
      }
  }
}

// layer 2: waves 0,1 -> z = H@W2l^T (bf16); waves 2,3 -> out = H@W2r^T + b2 (f32)
__global__ void __launch_bounds__(256, 2)
k_gemm2(const unsigned short* __restrict__ H, const unsigned short* __restrict__ Wpk,
        const float* __restrict__ bias, unsigned short* __restrict__ Zb,
        float* __restrict__ Out, int M) {
  __shared__ unsigned short At[64 * 256];
  int mBase = blockIdx.x * 64;
  stage_single(H, mBase, At);
  int lane = threadIdx.x & 63, wave = threadIdx.x >> 6;
  int l15 = lane & 15, quad = lane >> 4;
  floatx4 acc[4][4] = {};
  __syncthreads();
#pragma unroll 2
  for (int kk = 0; kk < 8; ++kk) {
    int kc = kk * 4 + quad;
    short8 b[4];
#pragma unroll
    for (int t = 0; t < 4; ++t) {
      int n = wave * 64 + t * 16 + l15;
      b[t] = *reinterpret_cast<const short8*>(Wpk + (size_t)n * 256 + kc * 8);
    }
#pragma unroll
    for (int s = 0; s < 4; ++s) {
      int row = s * 16 + l15;
      int pos = (kc & 16) | ((kc ^ row) & 15);
      short8 a = *reinterpret_cast<const short8*>(&At[row * 256 + pos * 8]);
#pragma unroll
      for (int t = 0; t < 4; ++t)
        acc[s][t] = __builtin_amdgcn_mfma_f32_16x16x32_bf16(a, b[t], acc[s][t], 0, 0, 0);
    }
  }
  if (wave < 2) {        // z path, cols 0..127, bf16, no bias
#pragma unroll
    for (int t = 0; t < 4; ++t) {
      int n = wave * 64 + t * 16 + l15;
#pragma unroll
      for (int s = 0; s < 4; ++s)
#pragma unroll
        for (int r = 0; r < 4; ++r) {
          int m = mBase + s * 16 + quad * 4 + r;
          if (m < M) Zb[(size_t)m * 128 + n] = f2b(acc[s][t][r]);
        }
    }
  } else {               // out path, cols 0..127 of Out, f32 + bias
#pragma unroll
    for (int t = 0; t < 4; ++t) {
      int n = (wave - 2) * 64 + t * 16 + l15;
      float bv = bias[n];
#pragma unroll
      for (int s = 0; s < 4; ++s)
#pragma unroll
        for (int r = 0; r < 4; ++r) {
          int m = mBase + s * 16 + quad * 4 + r;
          if (m < M) Out[(size_t)m * 128 + n] = acc[s][t][r] + bv;
        }
    }
  }
}

// ---------------- launch ----------------

extern "C" void kernel_launch(void* const* d_in, const int* in_sizes, int n_in,
                              void* d_out, int out_size, void* d_ws, size_t ws_size,
                              hipStream_t stream) {
  const float* x   = (const float*)d_in[0];
  const int*   ei  = (const int*)d_in[1];
  const float* W1l = (const float*)d_in[2];
  const float* b1  = (const float*)d_in[3];
  const float* W1r = (const float*)d_in[4];
  const float* W2l = (const float*)d_in[5];
  const float* b2  = (const float*)d_in[6];
  const float* W2r = (const float*)d_in[7];
  float* out = (float*)d_out;

  int N = in_sizes[0] / IN_C;   // 50000
  int E = in_sizes[1] / 2;      // 800000

  char* p = (char*)d_ws;
  auto alloc = [&](size_t bytes) -> void* {
    void* r = (void*)p;
    p += (bytes + 255) & ~(size_t)255;
    return r;
  };
  int* deg    = (int*)alloc((size_t)N * 4);
  int* offs   = (int*)alloc(((size_t)N + 1) * 4);
  int* cursor = (int*)alloc((size_t)N * 4);
  int* srcs   = (int*)alloc((size_t)E * 4);
  unsigned* xb   = (unsigned*)alloc((size_t)N * IN_C * 2);   // N x 64 uints
  unsigned* agg1 = (unsigned*)alloc((size_t)N * IN_C * 2);
  unsigned short* hb = (unsigned short*)alloc((size_t)N * HID_C * 2);
  unsigned short* zb = (unsigned short*)alloc((size_t)N * OUT_C * 2);
  unsigned* wpk1 = (unsigned*)alloc((size_t)HID_C * 256 * 2);  // 256 x 128 uints
  unsigned* wpk2 = (unsigned*)alloc((size_t)256 * HID_C * 2);  // 256 x 128 uints
  (void)alloc(64 * 512);   // tail pad for last-block over-reads

  // CSR build
  hipMemsetAsync(deg, 0, (size_t)N * 4, stream);
  k_hist<<<(E + 255) / 256, 256, 0, stream>>>(ei, E, deg);
  k_scan<<<1, 1024, 0, stream>>>(deg, offs, cursor, N);
  k_scatter<<<(E + 255) / 256, 256, 0, stream>>>(ei, E, cursor, srcs);

  // casts + weight packing
  k_cast<<<768, 256, 0, stream>>>(x, xb, N * IN_C / 2);
  k_pack1<<<128, 256, 0, stream>>>(W1l, W1r, wpk1);
  k_cast<<<32, 256, 0, stream>>>(W2l, wpk2, OUT_C * HID_C / 2);
  k_cast<<<32, 256, 0, stream>>>(W2r, wpk2 + (size_t)OUT_C * HID_C / 2, OUT_C * HID_C / 2);

  int aggX = (N + 3) / 4;
  int mBlocks = (N + 63) / 64;

  // layer 1
  k_agg_store<<<aggX, 256, 0, stream>>>(xb, offs, srcs, agg1, N);
  k_gemm1<<<mBlocks, 256, 0, stream>>>(
      (const unsigned short*)agg1, (const unsigned short*)xb,
      (const unsigned short*)wpk1, b1, hb, N);

  // layer 2 (reassociated)
  k_gemm2<<<mBlocks, 256, 0, stream>>>(
      hb, (const unsigned short*)wpk2, b2, zb, out, N);
  k_agg_addout<<<aggX, 256, 0, stream>>>((const unsigned*)zb, offs, srcs, out, N);
}

// Round 5
// 267.772 us; speedup vs baseline: 1.8676x; 1.3608x over previous
//
#include <hip/hip_runtime.h>
#include <hip/hip_bf16.h>

// GraphSAGE 2-layer encoder, MI355X. Round 5.
// - CSR build replaced by bucket-binned sort (dst>>7, 391 buckets):
//   LDS-aggregated bucket hist -> tiny 391-scan -> LDS-staged binning with
//   coalesced run flush -> per-bucket finalize (offs + srcs, L2-local writes).
//   Kills the 16x write amplification of the random 4B scatter and the
//   single-block 50000-element scan.
// - Aggregation: wave-per-node full-row gather, 8-deep unroll (round-4, kept).
// - GEMMs: 64x256 tile, K staged once into 32KB LDS via global_load_lds(16B),
//   XOR swizzle (round-3, kept). Layer 2 reassociated (z = h@W2l^T first).

typedef short short8 __attribute__((ext_vector_type(8)));
typedef float floatx4 __attribute__((ext_vector_type(4)));

#define IN_C  128
#define HID_C 256
#define OUT_C 128
#define NBMAX 400      // buckets of 128 nodes: ceil(50000/128)=391
#define CHUNK 12288    // edges staged per binning block (48 KB LDS)

static __device__ __forceinline__ unsigned short f2b(float f) {
  union { float f; unsigned u; } v; v.f = f;
  unsigned r = v.u + 0x7fffu + ((v.u >> 16) & 1u);   // RNE
  return (unsigned short)(r >> 16);
}
static __device__ __forceinline__ unsigned pack2(float a, float b) {
  return (unsigned)f2b(a) | ((unsigned)f2b(b) << 16);
}
static __device__ __forceinline__ float lo2f(unsigned u) {
  union { unsigned u; float f; } v; v.u = u << 16; return v.f;
}
static __device__ __forceinline__ float hi2f(unsigned u) {
  union { unsigned u; float f; } v; v.u = u & 0xffff0000u; return v.f;
}

// ---------------- CSR build (bucket-binned) ----------------

// 1) bucket histogram, LDS-aggregated
__global__ void k_bhist(const int* __restrict__ ei, int E, int nb,
                        int* __restrict__ bcounts) {
  __shared__ int lh[NBMAX];
  int tid = threadIdx.x;                       // 512
  for (int i = tid; i < nb; i += blockDim.x) lh[i] = 0;
  __syncthreads();
  int stride = gridDim.x * blockDim.x;
  for (int e = blockIdx.x * blockDim.x + tid; e < E; e += stride)
    atomicAdd(&lh[((unsigned)ei[E + e]) >> 7], 1);
  __syncthreads();
  for (int i = tid; i < nb; i += blockDim.x)
    if (lh[i]) atomicAdd(&bcounts[i], lh[i]);
}

// 2) exclusive scan (generic; used on nb=391 -> single iteration)
__global__ void k_scan(const int* __restrict__ deg, int* __restrict__ offs,
                       int* __restrict__ cursor, int n) {
  __shared__ int wsum[16];
  __shared__ int carry_s;
  int tid = threadIdx.x, lane = tid & 63, wv = tid >> 6;
  if (tid == 0) carry_s = 0;
  __syncthreads();
  for (int base = 0; base < n; base += 1024) {
    int idx = base + tid;
    int v = (idx < n) ? deg[idx] : 0;
    int s = v;
#pragma unroll
    for (int off = 1; off < 64; off <<= 1) {
      int t = __shfl_up(s, off, 64);
      if (lane >= off) s += t;
    }
    if (lane == 63) wsum[wv] = s;
    __syncthreads();
    if (wv == 0 && lane < 16) {
      int t = wsum[lane];
#pragma unroll
      for (int off = 1; off < 16; off <<= 1) {
        int u = __shfl_up(t, off, 64);
        if (lane >= off) t += u;
      }
      wsum[lane] = t;
    }
    __syncthreads();
    int woff = (wv == 0) ? 0 : wsum[wv - 1];
    int carry = carry_s;
    int excl = carry + woff + s - v;
    if (idx < n) { offs[idx] = excl; cursor[idx] = excl; }
    __syncthreads();
    if (tid == 0) carry_s = carry + wsum[15];
    __syncthreads();
  }
  if (tid == 0) offs[n] = carry_s;
}

// 3) binning: stage CHUNK edges in LDS per block, flush bucket runs coalesced.
//    staged value = (src<<7) | (dst&127)
__global__ void __launch_bounds__(1024, 1)
k_binplace(const int* __restrict__ ei, int E, int nb,
           int* __restrict__ cursor, unsigned* __restrict__ staged) {
  __shared__ unsigned sbuf[CHUNK];
  __shared__ int lh[1024];       // padded hist / scan input
  __shared__ int loff[NBMAX];    // local exclusive offsets
  __shared__ int lcnt[NBMAX];
  __shared__ int lcur[NBMAX];
  __shared__ int gb[NBMAX];      // global run base per bucket
  __shared__ int wsum[16];
  int tid = threadIdx.x, lane = tid & 63, wv = tid >> 6;
  int e0 = blockIdx.x * CHUNK;
  int e1 = min(e0 + CHUNK, E);
  lh[tid] = 0;
  __syncthreads();
  for (int e = e0 + tid; e < e1; e += 1024)
    atomicAdd(&lh[((unsigned)ei[E + e]) >> 7], 1);
  __syncthreads();
  // block-wide exclusive scan of lh[0..1023]
  int v = lh[tid];
  int s = v;
#pragma unroll
  for (int off = 1; off < 64; off <<= 1) {
    int t = __shfl_up(s, off, 64);
    if (lane >= off) s += t;
  }
  if (lane == 63) wsum[wv] = s;
  __syncthreads();
  if (wv == 0 && lane < 16) {
    int t = wsum[lane];
#pragma unroll
    for (int off = 1; off < 16; off <<= 1) {
      int u = __shfl_up(t, off, 64);
      if (lane >= off) t += u;
    }
    wsum[lane] = t;
  }
  __syncthreads();
  int woff = (wv == 0) ? 0 : wsum[wv - 1];
  int excl = woff + s - v;
  if (tid < nb) {
    loff[tid] = excl; lcnt[tid] = v; lcur[tid] = excl;
    gb[tid] = atomicAdd(&cursor[tid], v);
  }
  __syncthreads();
  // local placement
  for (int e = e0 + tid; e < e1; e += 1024) {
    int dst = ei[E + e];
    int src = ei[e];
    int b = ((unsigned)dst) >> 7;
    int p = atomicAdd(&lcur[b], 1);
    sbuf[p] = ((unsigned)src << 7) | (unsigned)(dst & 127);
  }
  __syncthreads();
  // coalesced flush: wave per bucket (strided)
  for (int b = wv; b < nb; b += 16) {
    int lbeg = loff[b], cnt = lcnt[b], gbase = gb[b];
    for (int p = lane; p < cnt; p += 64)
      staged[gbase + p] = sbuf[lbeg + p];
  }
}

// 4) finalize: per-bucket offs + srcs
__global__ void k_csr(const unsigned* __restrict__ staged, const int* __restrict__ bbase,
                      int* __restrict__ offs, int* __restrict__ srcs, int N, int E) {
  __shared__ int cnt[128];
  __shared__ int cur[128];
  int b = blockIdx.x;
  int tid = threadIdx.x;                  // 256
  int gbeg = bbase[b], gend = bbase[b + 1];
  if (tid < 128) cnt[tid] = 0;
  __syncthreads();
  for (int j = gbeg + tid; j < gend; j += 256)
    atomicAdd(&cnt[staged[j] & 127], 1);
  __syncthreads();
  if (tid < 64) {
    int v0 = cnt[tid * 2], v1 = cnt[tid * 2 + 1];
    int s = v0 + v1;
#pragma unroll
    for (int off = 1; off < 64; off <<= 1) {
      int t = __shfl_up(s, off, 64);
      if (tid >= off) s += t;
    }
    int exclp = s - (v0 + v1);
    int node = b * 128 + tid * 2;
    cur[tid * 2]     = gbeg + exclp;
    cur[tid * 2 + 1] = gbeg + exclp + v0;
    if (node < N)     offs[node]     = gbeg + exclp;
    if (node + 1 < N) offs[node + 1] = gbeg + exclp + v0;
  }
  __syncthreads();
  for (int j = gbeg + tid; j < gend; j += 256) {
    unsigned v = staged[j];
    int pos = atomicAdd(&cur[v & 127], 1);
    srcs[pos] = (int)(v >> 7);
  }
  if (b == 0 && tid == 0) offs[N] = E;
}

// ---------------- casts / packing ----------------

__global__ void k_cast(const float* __restrict__ in, unsigned* __restrict__ out, int nPairs) {
  int i = blockIdx.x * blockDim.x + threadIdx.x;
  int stride = gridDim.x * blockDim.x;
  for (; i < nPairs; i += stride) {
    float2 v = reinterpret_cast<const float2*>(in)[i];
    out[i] = pack2(v.x, v.y);
  }
}

__global__ void k_pack1(const float* __restrict__ Wl, const float* __restrict__ Wr,
                        unsigned* __restrict__ out) {
  int i = blockIdx.x * blockDim.x + threadIdx.x;    // 256*128 pairs
  if (i >= 256 * 128) return;
  int r = i >> 7, c = i & 127;
  const float* src = (c < 64) ? (Wl + (size_t)r * 128 + c * 2)
                              : (Wr + (size_t)r * 128 + (c - 64) * 2);
  float2 v = *reinterpret_cast<const float2*>(src);
  out[i] = pack2(v.x, v.y);
}

// ---------------- mean aggregation: wave per node, full 256 B row ----------------

__global__ void k_agg_store(const unsigned* __restrict__ Z,
                            const int* __restrict__ offs, const int* __restrict__ srcs,
                            unsigned* __restrict__ out, int N) {
  int node = blockIdx.x * 4 + (threadIdx.x >> 6);
  if (node >= N) return;
  int lane = threadIdx.x & 63;
  int beg = offs[node], end = offs[node + 1];
  float s0 = 0.f, s1 = 0.f;
  int j = beg;
  for (; j + 8 <= end; j += 8) {
    unsigned p0 = Z[(size_t)srcs[j + 0] * 64 + lane];
    unsigned p1 = Z[(size_t)srcs[j + 1] * 64 + lane];
    unsigned p2 = Z[(size_t)srcs[j + 2] * 64 + lane];
    unsigned p3 = Z[(size_t)srcs[j + 3] * 64 + lane];
    unsigned p4 = Z[(size_t)srcs[j + 4] * 64 + lane];
    unsigned p5 = Z[(size_t)srcs[j + 5] * 64 + lane];
    unsigned p6 = Z[(size_t)srcs[j + 6] * 64 + lane];
    unsigned p7 = Z[(size_t)srcs[j + 7] * 64 + lane];
    s0 += lo2f(p0) + lo2f(p1) + lo2f(p2) + lo2f(p3)
        + lo2f(p4) + lo2f(p5) + lo2f(p6) + lo2f(p7);
    s1 += hi2f(p0) + hi2f(p1) + hi2f(p2) + hi2f(p3)
        + hi2f(p4) + hi2f(p5) + hi2f(p6) + hi2f(p7);
  }
  for (; j < end; ++j) {
    unsigned p = Z[(size_t)srcs[j] * 64 + lane];
    s0 += lo2f(p); s1 += hi2f(p);
  }
  int d = end - beg;
  float inv = 1.0f / (float)(d > 0 ? d : 1);
  out[(size_t)node * 64 + lane] = pack2(s0 * inv, s1 * inv);
}

__global__ void k_agg_addout(const unsigned* __restrict__ Z,
                             const int* __restrict__ offs, const int* __restrict__ srcs,
                             float* __restrict__ Out, int N) {
  int node = blockIdx.x * 4 + (threadIdx.x >> 6);
  if (node >= N) return;
  int lane = threadIdx.x & 63;
  int beg = offs[node], end = offs[node + 1];
  float s0 = 0.f, s1 = 0.f;
  int j = beg;
  for (; j + 8 <= end; j += 8) {
    unsigned p0 = Z[(size_t)srcs[j + 0] * 64 + lane];
    unsigned p1 = Z[(size_t)srcs[j + 1] * 64 + lane];
    unsigned p2 = Z[(size_t)srcs[j + 2] * 64 + lane];
    unsigned p3 = Z[(size_t)srcs[j + 3] * 64 + lane];
    unsigned p4 = Z[(size_t)srcs[j + 4] * 64 + lane];
    unsigned p5 = Z[(size_t)srcs[j + 5] * 64 + lane];
    unsigned p6 = Z[(size_t)srcs[j + 6] * 64 + lane];
    unsigned p7 = Z[(size_t)srcs[j + 7] * 64 + lane];
    s0 += lo2f(p0) + lo2f(p1) + lo2f(p2) + lo2f(p3)
        + lo2f(p4) + lo2f(p5) + lo2f(p6) + lo2f(p7);
    s1 += hi2f(p0) + hi2f(p1) + hi2f(p2) + hi2f(p3)
        + hi2f(p4) + hi2f(p5) + hi2f(p6) + hi2f(p7);
  }
  for (; j < end; ++j) {
    unsigned p = Z[(size_t)srcs[j] * 64 + lane];
    s0 += lo2f(p); s1 += hi2f(p);
  }
  int d = end - beg;
  float inv = 1.0f / (float)(d > 0 ? d : 1);
  float2* op = reinterpret_cast<float2*>(Out + (size_t)node * 128 + lane * 2);
  float2 v = *op;
  v.x += s0 * inv; v.y += s1 * inv;
  *op = v;
}

// ---------------- GEMMs (round-3 structure) ----------------

static __device__ __forceinline__ void stage_dual(
    const unsigned short* A1, const unsigned short* A2, int mBase,
    unsigned short* At /* LDS 64x256 */) {
  int t = threadIdx.x;
#pragma unroll
  for (int it = 0; it < 8; ++it) {
    int q = it * 256 + t;
    int r = q >> 5;
    int p = q & 31;
    int d = (p & 16) | ((p ^ r) & 15);
    const unsigned short* g = (d < 16)
        ? (A1 + (size_t)(mBase + r) * 128 + d * 8)
        : (A2 + (size_t)(mBase + r) * 128 + (d - 16) * 8);
    __builtin_amdgcn_global_load_lds(
        (const __attribute__((address_space(1))) unsigned*)g,
        (__attribute__((address_space(3))) unsigned*)&At[q * 8], 16, 0, 0);
  }
}

static __device__ __forceinline__ void stage_single(
    const unsigned short* A, int mBase, unsigned short* At) {
  int t = threadIdx.x;
#pragma unroll
  for (int it = 0; it < 8; ++it) {
    int q = it * 256 + t;
    int r = q >> 5;
    int p = q & 31;
    int d = (p & 16) | ((p ^ r) & 15);
    const unsigned short* g = A + (size_t)(mBase + r) * 256 + d * 8;
    __builtin_amdgcn_global_load_lds(
        (const __attribute__((address_space(1))) unsigned*)g,
        (__attribute__((address_space(3))) unsigned*)&At[q * 8], 16, 0, 0);
  }
}

__global__ void __launch_bounds__(256, 2)
k_gemm1(const unsigned short* __restrict__ A1, const unsigned short* __restrict__ A2,
        const unsigned short* __restrict__ Wpk, const float* __restrict__ bias,
        unsigned short* __restrict__ H, int M) {
  __shared__ unsigned short At[64 * 256];
  int mBase = blockIdx.x * 64;
  stage_dual(A1, A2, mBase, At);
  int lane = threadIdx.x & 63, wave = threadIdx.x >> 6;
  int l15 = lane & 15, quad = lane >> 4;
  floatx4 acc[4][4] = {};
  __syncthreads();
#pragma unroll 2
  for (int kk = 0; kk < 8; ++kk) {
    int kc = kk * 4 + quad;
    short8 b[4];
#pragma unroll
    for (int t = 0; t < 4; ++t) {
      int n = wave * 64 + t * 16 + l15;
      b[t] = *reinterpret_cast<const short8*>(Wpk + (size_t)n * 256 + kc * 8);
    }
#pragma unroll
    for (int s = 0; s < 4; ++s) {
      int row = s * 16 + l15;
      int pos = (kc & 16) | ((kc ^ row) & 15);
      short8 a = *reinterpret_cast<const short8*>(&At[row * 256 + pos * 8]);
#pragma unroll
      for (int t = 0; t < 4; ++t)
        acc[s][t] = __builtin_amdgcn_mfma_f32_16x16x32_bf16(a, b[t], acc[s][t], 0, 0, 0);
    }
  }
#pragma unroll
  for (int t = 0; t < 4; ++t) {
    int n = wave * 64 + t * 16 + l15;
    float bv = bias[n];
#pragma unroll
    for (int s = 0; s < 4; ++s)
#pragma unroll
      for (int r = 0; r < 4; ++r) {
        int m = mBase + s * 16 + quad * 4 + r;
        if (m < M) H[(size_t)m * 256 + n] = f2b(fmaxf(acc[s][t][r] + bv, 0.f));
      }
  }
}

__global__ void __launch_bounds__(256, 2)
k_gemm2(const unsigned short* __restrict__ H, const unsigned short* __restrict__ Wpk,
        const float* __restrict__ bias, unsigned short* __restrict__ Zb,
        float* __restrict__ Out, int M) {
  __shared__ unsigned short At[64 * 256];
  int mBase = blockIdx.x * 64;
  stage_single(H, mBase, At);
  int lane = threadIdx.x & 63, wave = threadIdx.x >> 6;
  int l15 = lane & 15, quad = lane >> 4;
  floatx4 acc[4][4] = {};
  __syncthreads();
#pragma unroll 2
  for (int kk = 0; kk < 8; ++kk) {
    int kc = kk * 4 + quad;
    short8 b[4];
#pragma unroll
    for (int t = 0; t < 4; ++t) {
      int n = wave * 64 + t * 16 + l15;
      b[t] = *reinterpret_cast<const short8*>(Wpk + (size_t)n * 256 + kc * 8);
    }
#pragma unroll
    for (int s = 0; s < 4; ++s) {
      int row = s * 16 + l15;
      int pos = (kc & 16) | ((kc ^ row) & 15);
      short8 a = *reinterpret_cast<const short8*>(&At[row * 256 + pos * 8]);
#pragma unroll
      for (int t = 0; t < 4; ++t)
        acc[s][t] = __builtin_amdgcn_mfma_f32_16x16x32_bf16(a, b[t], acc[s][t], 0, 0, 0);
    }
  }
  if (wave < 2) {        // z path, cols 0..127, bf16, no bias
#pragma unroll
    for (int t = 0; t < 4; ++t) {
      int n = wave * 64 + t * 16 + l15;
#pragma unroll
      for (int s = 0; s < 4; ++s)
#pragma unroll
        for (int r = 0; r < 4; ++r) {
          int m = mBase + s * 16 + quad * 4 + r;
          if (m < M) Zb[(size_t)m * 128 + n] = f2b(acc[s][t][r]);
        }
    }
  } else {               // out path, cols 0..127 of Out, f32 + bias
#pragma unroll
    for (int t = 0; t < 4; ++t) {
      int n = (wave - 2) * 64 + t * 16 + l15;
      float bv = bias[n];
#pragma unroll
      for (int s = 0; s < 4; ++s)
#pragma unroll
        for (int r = 0; r < 4; ++r) {
          int m = mBase + s * 16 + quad * 4 + r;
          if (m < M) Out[(size_t)m * 128 + n] = acc[s][t][r] + bv;
        }
    }
  }
}

// ---------------- launch ----------------

extern "C" void kernel_launch(void* const* d_in, const int* in_sizes, int n_in,
                              void* d_out, int out_size, void* d_ws, size_t ws_size,
                              hipStream_t stream) {
  const float* x   = (const float*)d_in[0];
  const int*   ei  = (const int*)d_in[1];
  const float* W1l = (const float*)d_in[2];
  const float* b1  = (const float*)d_in[3];
  const float* W1r = (const float*)d_in[4];
  const float* W2l = (const float*)d_in[5];
  const float* b2  = (const float*)d_in[6];
  const float* W2r = (const float*)d_in[7];
  float* out = (float*)d_out;

  int N = in_sizes[0] / IN_C;   // 50000
  int E = in_sizes[1] / 2;      // 800000
  int nb = (N + 127) >> 7;      // 391

  char* p = (char*)d_ws;
  auto alloc = [&](size_t bytes) -> void* {
    void* r = (void*)p;
    p += (bytes + 255) & ~(size_t)255;
    return r;
  };
  int* bcounts = (int*)alloc((size_t)(nb + 1) * 4);
  int* bbase   = (int*)alloc((size_t)(nb + 1) * 4);
  int* cursor  = (int*)alloc((size_t)(nb + 1) * 4);
  unsigned* staged = (unsigned*)alloc((size_t)E * 4);
  int* offs   = (int*)alloc(((size_t)N + 1) * 4);
  int* srcs   = (int*)alloc((size_t)E * 4);
  unsigned* xb   = (unsigned*)alloc((size_t)N * IN_C * 2);   // N x 64 uints
  unsigned* agg1 = (unsigned*)alloc((size_t)N * IN_C * 2);
  unsigned short* hb = (unsigned short*)alloc((size_t)N * HID_C * 2);
  unsigned short* zb = (unsigned short*)alloc((size_t)N * OUT_C * 2);
  unsigned* wpk1 = (unsigned*)alloc((size_t)HID_C * 256 * 2);  // 256 x 128 uints
  unsigned* wpk2 = (unsigned*)alloc((size_t)256 * HID_C * 2);  // 256 x 128 uints
  (void)alloc(64 * 512);   // tail pad for last-block over-reads

  // CSR build (binned)
  hipMemsetAsync(bcounts, 0, (size_t)(nb + 1) * 4, stream);
  k_bhist<<<256, 512, 0, stream>>>(ei, E, nb, bcounts);
  k_scan<<<1, 1024, 0, stream>>>(bcounts, bbase, cursor, nb);
  k_binplace<<<(E + CHUNK - 1) / CHUNK, 1024, 0, stream>>>(ei, E, nb, cursor, staged);
  k_csr<<<nb, 256, 0, stream>>>(staged, bbase, offs, srcs, N, E);

  // casts + weight packing
  k_cast<<<768, 256, 0, stream>>>(x, xb, N * IN_C / 2);
  k_pack1<<<128, 256, 0, stream>>>(W1l, W1r, wpk1);
  k_cast<<<32, 256, 0, stream>>>(W2l, wpk2, OUT_C * HID_C / 2);
  k_cast<<<32, 256, 0, stream>>>(W2r, wpk2 + (size_t)OUT_C * HID_C / 2, OUT_C * HID_C / 2);

  int aggX = (N + 3) / 4;
  int mBlocks = (N + 63) / 64;

  // layer 1
  k_agg_store<<<aggX, 256, 0, stream>>>(xb, offs, srcs, agg1, N);
  k_gemm1<<<mBlocks, 256, 0, stream>>>(
      (const unsigned short*)agg1, (const unsigned short*)xb,
      (const unsigned short*)wpk1, b1, hb, N);

  // layer 2 (reassociated)
  k_gemm2<<<mBlocks, 256, 0, stream>>>(
      hb, (const unsigned short*)wpk2, b2, zb, out, N);
  k_agg_addout<<<aggX, 256, 0, stream>>>((const unsigned*)zb, offs, srcs, out, N);
}